// Round 6
// baseline (30355.518 us; speedup 1.0000x reference)
//
#include <hip/hip_runtime.h>
#include <hip/hip_cooperative_groups.h>

namespace cg = cooperative_groups;

// ---------------------------------------------------------------------------
// LayerNorm-LSTM (2 layers) + softmax head.  B=1024 T=100 D=300 U=512 C=14
// Round 9:
//   - loop stuck at 48-54 us/iter across 4 inner-loop variants (r2,r4,r5):
//     invariant cost = 202 launches (~15-19 us/iter overhead+drain).
//   - persistent cooperative kernel: whole t-loop in ONE dispatch, 512
//     blocks (2/CU, launch_bounds(256,2), 17.4KB LDS), grid.sync between
//     GEMM phase and LN phase.  Same math as r5 (device-fn refactor).
//   - fallback to r5 multi-launch loop if coop unsupported/failed.
//   - gemm_x0: xs stride 328->340 f16 (bank-conflict fix, was 1.6e7).
// ---------------------------------------------------------------------------

typedef _Float16 f16;
typedef _Float16 f16x8 __attribute__((ext_vector_type(8)));
typedef _Float16 f16x4 __attribute__((ext_vector_type(4)));
typedef float f32x4 __attribute__((ext_vector_type(4)));

// ---------------------------------------------------------------------------
// W [K,N] fp32 row-major -> Bt [N,Kp] f16 row-major at column offset k_off.
// ---------------------------------------------------------------------------
__global__ __launch_bounds__(256) void transpose_f16(
    const float* __restrict__ W, f16* __restrict__ Bt, int K, int N, int Kp,
    int k_off) {
  __shared__ float s[32][33];
  int n0 = blockIdx.x * 32, k0 = blockIdx.y * 32;
  int tid = threadIdx.x, c = tid & 31, r8 = tid >> 5;
  for (int rr = r8; rr < 32; rr += 8) {
    int k = k0 + rr;
    s[rr][c] = (k < K) ? W[(long)k * N + (n0 + c)] : 0.0f;
  }
  __syncthreads();
  for (int rr = r8; rr < 32; rr += 8)
    Bt[(long)(n0 + rr) * Kp + k_off + (k0 + c)] = (f16)s[c][rr];
}

#define MFMAS(AF, BF)                                                                   \
  acc[0][0] = __builtin_amdgcn_mfma_f32_16x16x32_f16(AF[0], BF[0], acc[0][0], 0, 0, 0); \
  acc[0][1] = __builtin_amdgcn_mfma_f32_16x16x32_f16(AF[0], BF[1], acc[0][1], 0, 0, 0); \
  acc[1][0] = __builtin_amdgcn_mfma_f32_16x16x32_f16(AF[1], BF[0], acc[1][0], 0, 0, 0); \
  acc[1][1] = __builtin_amdgcn_mfma_f32_16x16x32_f16(AF[1], BF[1], acc[1][1], 0, 0, 0); \
  acc[2][0] = __builtin_amdgcn_mfma_f32_16x16x32_f16(AF[2], BF[0], acc[2][0], 0, 0, 0); \
  acc[2][1] = __builtin_amdgcn_mfma_f32_16x16x32_f16(AF[2], BF[1], acc[2][1], 0, 0, 0); \
  acc[3][0] = __builtin_amdgcn_mfma_f32_16x16x32_f16(AF[3], BF[0], acc[3][0], 0, 0, 0); \
  acc[3][1] = __builtin_amdgcn_mfma_f32_16x16x32_f16(AF[3], BF[1], acc[3][1], 0, 0, 0);

// A row stride fixed 1024 (h01); B row stride LDB.
#define LOADAB(AF, BF, A0, B0, LDB, K0)                    \
  AF[0] = *(const f16x8*)((A0) + (K0));                    \
  AF[1] = *(const f16x8*)((A0) + 16 * 1024 + (K0));        \
  AF[2] = *(const f16x8*)((A0) + 32 * 1024 + (K0));        \
  AF[3] = *(const f16x8*)((A0) + 48 * 1024 + (K0));        \
  BF[0] = *(const f16x8*)((B0) + (K0));                    \
  BF[1] = *(const f16x8*)((B0) + 16 * (LDB) + (K0));

// 4-deep register-pipelined K-loop (KTOT multiple of 128, >= 256).
#define GEMM_PIPE4(A0, B0, LDB, KTOT)                            \
  {                                                              \
    f16x8 aA[4], bA[2], aB[4], bB[2];                            \
    f16x8 aC[4], bC[2], aD[4], bD[2];                            \
    LOADAB(aA, bA, A0, B0, LDB, 0)                               \
    LOADAB(aB, bB, A0, B0, LDB, 32)                              \
    LOADAB(aC, bC, A0, B0, LDB, 64)                              \
    LOADAB(aD, bD, A0, B0, LDB, 96)                              \
    for (int k0 = 0; k0 + 224 < (KTOT); k0 += 128) {             \
      MFMAS(aA, bA) LOADAB(aA, bA, A0, B0, LDB, k0 + 128)        \
      MFMAS(aB, bB) LOADAB(aB, bB, A0, B0, LDB, k0 + 160)        \
      MFMAS(aC, bC) LOADAB(aC, bC, A0, B0, LDB, k0 + 192)       \
      MFMAS(aD, bD) LOADAB(aD, bD, A0, B0, LDB, k0 + 224)        \
    }                                                            \
    MFMAS(aA, bA) MFMAS(aB, bB) MFMAS(aC, bC) MFMAS(aD, bD)      \
  }

// ---------------------------------------------------------------------------
// Upfront GEMM: z0x[t][b][n] = (f16) sum_k x[b,t,k] * W0[k,n]
// One block per 64-row M-stripe; x staged to LDS f16 once; 16 N-chunks.
// xs row stride 340 f16 (=170 dwords, l15*10 mod 32 all-distinct -> 2-way).
// ---------------------------------------------------------------------------
__global__ __launch_bounds__(256) void gemm_x0(
    const float* __restrict__ x, const f16* __restrict__ W0t,
    f16* __restrict__ z0x) {
  __shared__ f16 xs[64][340];
  __shared__ f16 st[64][136];
  int tid = threadIdx.x;
  long bm0 = (long)blockIdx.x * 64;

  for (int p = 0; p < 20; ++p) {
    unsigned idx = (unsigned)tid + p * 256u;  // [0, 5120)
    unsigned r = idx / 80u, s = idx - r * 80u;
    f16x4 h4 = {};
    if (s < 75u) {
      f32x4 v = *(const f32x4*)(x + (bm0 + r) * 300L + s * 4u);
      h4[0] = (f16)v[0]; h4[1] = (f16)v[1];
      h4[2] = (f16)v[2]; h4[3] = (f16)v[3];
    }
    *(f16x4*)&xs[r][s * 4u] = h4;
  }
  __syncthreads();

  int lane = tid & 63, w = tid >> 6;
  int l15 = lane & 15, quad = lane >> 4;

  for (int nc = 0; nc < 16; ++nc) {
    long bn0 = (long)nc * 128 + w * 32;
    const f16* bw = W0t + (bn0 + l15) * 320L + quad * 8;
    f32x4 acc[4][2] = {};
#pragma unroll
    for (int k0 = 0; k0 < 320; k0 += 32) {
      f16x8 af[4], bf[2];
#pragma unroll
      for (int i = 0; i < 4; ++i)
        af[i] = *(const f16x8*)&xs[l15 + i * 16][quad * 8 + k0];
      bf[0] = *(const f16x8*)(bw + k0);
      bf[1] = *(const f16x8*)(bw + 16 * 320 + k0);
      MFMAS(af, bf)
    }
    __syncthreads();
#pragma unroll
    for (int i = 0; i < 4; ++i)
#pragma unroll
      for (int j = 0; j < 2; ++j)
#pragma unroll
        for (int r = 0; r < 4; ++r)
          st[i * 16 + quad * 4 + r][w * 32 + j * 16 + l15] = (f16)acc[i][j][r];
    __syncthreads();
    {
      int r = tid >> 2, cc = (tid & 3) * 32;
      unsigned rr = (unsigned)(bm0 + r);
      unsigned b = rr / 100u, t = rr - b * 100u;
      f16* dst = z0x + (long)t * 2097152 + (long)b * 2048 + nc * 128 + cc;
      const f16x8* s8 = (const f16x8*)&st[r][cc];
      f16x8* d8 = (f16x8*)dst;
      d8[0] = s8[0]; d8[1] = s8[1]; d8[2] = s8[2]; d8[3] = s8[3];
    }
  }
}

// ---------------------------------------------------------------------------
// Device fn: one 64x128 GEMM tile of the per-step problem.
//   prob 0: zA = [x_t@W0 or cin0] + h0 @ U0      (z0 at step t)
//   prob 1: zB = h01 @ WU1t  (K=1024)            (z1 at step t-1)
// ---------------------------------------------------------------------------
__device__ __forceinline__ void gemm_tile(
    int prob, int xblk, int y, int tid,
    const float* __restrict__ xt, const f16* __restrict__ h01,
    const f16* __restrict__ W0t, const f16* __restrict__ U0t,
    const f16* __restrict__ WU1t, const f16* __restrict__ cin0,
    f16* __restrict__ zA, f16* __restrict__ zB, f16 (*st)[136]) {
  int lane = tid & 63, w = tid >> 6;
  int l15 = lane & 15, quad = lane >> 4;
  long bn0 = (long)xblk * 128 + w * 32;
  long bm0 = (long)(y & 15) * 64;
  long arow = (bm0 + l15) * 1024 + quad * 8;

  f32x4 acc[4][2] = {};

  if (prob == 0) {
    if (!cin0) {
      // in-kernel x_t @ W0 (K=300: phases 0..256 + guarded tail)
      const float* ax = xt + (bm0 + l15) * 30000L + quad * 8;
      const f16* bw = W0t + (bn0 + l15) * 320L + quad * 8;
#pragma unroll
      for (int k0 = 0; k0 < 288; k0 += 32) {
        f16x8 af[4], bf[2];
#pragma unroll
        for (int i = 0; i < 4; ++i) {
          f32x4 lo = *(const f32x4*)(ax + (long)i * 480000 + k0);
          f32x4 hi = *(const f32x4*)(ax + (long)i * 480000 + k0 + 4);
#pragma unroll
          for (int e = 0; e < 4; ++e) {
            af[i][e] = (f16)lo[e];
            af[i][4 + e] = (f16)hi[e];
          }
        }
        bf[0] = *(const f16x8*)(bw + k0);
        bf[1] = *(const f16x8*)(bw + 16 * 320 + k0);
        MFMAS(af, bf)
      }
      {
        f16x8 af[4], bf[2];
#pragma unroll
        for (int i = 0; i < 4; ++i) {
          long rb = (bm0 + l15 + i * 16) * 30000L;
#pragma unroll
          for (int e = 0; e < 8; ++e) {
            int k = 288 + quad * 8 + e;
            af[i][e] = (k < 300) ? (f16)xt[rb + k] : (f16)0.f;
          }
        }
        bf[0] = *(const f16x8*)(bw + 288);
        bf[1] = *(const f16x8*)(bw + 16 * 320 + 288);
        MFMAS(af, bf)
      }
    }
    const f16* a0 = h01 + arow;
    const f16* b0 = U0t + (bn0 + l15) * 512L + quad * 8;
    GEMM_PIPE4(a0, b0, 512, 512)
  } else {
    const f16* a0 = h01 + arow;
    const f16* b0 = WU1t + (bn0 + l15) * 1024L + quad * 8;
    GEMM_PIPE4(a0, b0, 1024, 1024)
  }

  // epilogue: +Cin (fp32), stage f16 to LDS, coalesced 64B stores
#pragma unroll
  for (int i = 0; i < 4; ++i) {
#pragma unroll
    for (int j = 0; j < 2; ++j) {
#pragma unroll
      for (int r = 0; r < 4; ++r) {
        float v = acc[i][j][r];
        if (prob == 0 && cin0) {
          long row = bm0 + i * 16 + quad * 4 + r;
          long col = bn0 + j * 16 + l15;
          v += (float)cin0[row * 2048 + col];
        }
        st[i * 16 + quad * 4 + r][w * 32 + j * 16 + l15] = (f16)v;
      }
    }
  }
  __syncthreads();
  {
    f16* Z = prob ? zB : zA;
    int r = tid >> 2, cc = (tid & 3) * 32;
    f16* dst = Z + (bm0 + r) * 2048 + (long)xblk * 128 + cc;
    const f16x8* s8 = (const f16x8*)&st[r][cc];
    f16x8* d8 = (f16x8*)dst;
    d8[0] = s8[0]; d8[1] = s8[1]; d8[2] = s8[2]; d8[3] = s8[3];
  }
}

// ---------------------------------------------------------------------------
// Device fn: LN + gates + state update for one (layer, b) unit.
// ---------------------------------------------------------------------------
__device__ __forceinline__ void ln_unit(
    int layer, int b, int t,
    const f16* __restrict__ zA, const f16* __restrict__ zB,
    const float* __restrict__ g0, const float* __restrict__ be0,
    const float* __restrict__ bs0, const float* __restrict__ g1,
    const float* __restrict__ be1, const float* __restrict__ bs1,
    const int* __restrict__ mask, f16* __restrict__ h01,
    float* __restrict__ c0, float* __restrict__ c1, float* __restrict__ act) {
  int tid = threadIdx.x;
  const f16* z = layer ? zB : zA;
  const float* gamma = layer ? g1 : g0;
  const float* beta = layer ? be1 : be0;
  const float* bias = layer ? bs1 : bs0;
  f16* h = h01 + layer * 512;
  float* c = layer ? c1 : c0;
  int tm = layer ? (t - 1) : t;

  int w = tid >> 6, lane = tid & 63;

  f16x8 v8 = *(const f16x8*)(z + (long)b * 2048 + w * 512 + lane * 8);
  float zv[8];
  float sum = 0.0f, sq = 0.0f;
#pragma unroll
  for (int e = 0; e < 8; ++e) {
    float v = (float)v8[e];
    zv[e] = v;
    sum += v;
    sq += v * v;
  }
#pragma unroll
  for (int off = 32; off; off >>= 1) {
    sum += __shfl_xor(sum, off);
    sq += __shfl_xor(sq, off);
  }
  float mu = sum * (1.0f / 512.0f);
  float var = sq * (1.0f / 512.0f) - mu * mu;
  float is = rsqrtf(var + 1e-3f);

  int k = w * 512 + lane * 8;
#pragma unroll
  for (int i = 0; i < 2; ++i) {
    f32x4 g = *(const f32x4*)(gamma + k + 4 * i);
    f32x4 be = *(const f32x4*)(beta + k + 4 * i);
    f32x4 bi = *(const f32x4*)(bias + k + 4 * i);
    f32x4 av;
#pragma unroll
    for (int e = 0; e < 4; ++e) {
      float val = g[e] * (zv[4 * i + e] - mu) * is + be[e] + bi[e];
      float a;
      if (w == 2) {
        a = 2.0f / (1.0f + __expf(-2.0f * val)) - 1.0f;  // tanh
      } else {
        a = 1.0f / (1.0f + __expf(-val));                // sigmoid
      }
      av[e] = a;
    }
    *(f32x4*)(act + k + 4 * i) = av;
  }
  __syncthreads();

  bool m = mask[(long)b * 100 + tm] > 0;
#pragma unroll
  for (int i = 0; i < 2; ++i) {
    int u = tid + 256 * i;
    float co = c[(long)b * 512 + u];
    float ho = (float)h[(long)b * 1024 + u];
    float cn = act[512 + u] * co + act[u] * act[1024 + u];
    float th = 2.0f / (1.0f + __expf(-2.0f * cn)) - 1.0f;
    float hn = act[1536 + u] * th;
    h[(long)b * 1024 + u] = (f16)(m ? hn : ho);
    c[(long)b * 512 + u] = m ? cn : co;
  }
  __syncthreads();  // act reuse guard (next unit)
}

// ---------------------------------------------------------------------------
// Persistent cooperative kernel: whole t-loop, 512 blocks x 256 threads.
//   GEMM phase: block bid -> xblk=bid&15, y=bid>>4, prob=y>>4
//   LN phase:   block bid -> units bid*4 .. bid*4+3 (layer=u>>10, b=u&1023)
// ---------------------------------------------------------------------------
__global__ __launch_bounds__(256, 2) void lstm_loop(
    const float* x, const int* mask,
    const float* g0, const float* be0, const float* bs0,
    const float* g1, const float* be1, const float* bs1,
    f16* h01, float* c0, float* c1,
    const f16* W0t, const f16* U0t, const f16* WU1t,
    const f16* z0x, f16* zA, f16* zB) {
  cg::grid_group grid = cg::this_grid();
  __shared__ __align__(16) char smbuf[64 * 136 * 2];  // st(17408B) / act(8192B)
  f16(*st)[136] = reinterpret_cast<f16(*)[136]>(smbuf);
  float* act = reinterpret_cast<float*>(smbuf);

  int bid = blockIdx.x, tid = threadIdx.x;
  int xblk = bid & 15, y = bid >> 4, prob = y >> 4;

  for (int t = 0; t <= 100; ++t) {
    int do0 = (t < 100), do1 = (t >= 1);
    if (prob ? do1 : do0) {
      gemm_tile(prob, xblk, y, tid, x + (long)t * 300, h01, W0t, U0t, WU1t,
                z0x ? z0x + (long)t * 2097152 : nullptr, zA, zB, st);
    }
    __threadfence();
    grid.sync();
#pragma unroll 1
    for (int i = 0; i < 4; ++i) {
      int u = bid * 4 + i;
      int layer = u >> 10, b = u & 1023;
      if (layer ? do1 : do0)
        ln_unit(layer, b, t, zA, zB, g0, be0, bs0, g1, be1, bs1, mask, h01,
                c0, c1, act);
    }
    __threadfence();
    grid.sync();
  }
}

// ---------------------------------------------------------------------------
// Fallback wrappers (multi-launch path, r5 structure).
// ---------------------------------------------------------------------------
__global__ __launch_bounds__(256, 2) void gemm_step(
    const float* __restrict__ xt, const f16* __restrict__ h01,
    const f16* __restrict__ W0t, const f16* __restrict__ U0t,
    const f16* __restrict__ WU1t, const f16* __restrict__ cin0,
    f16* __restrict__ zA, f16* __restrict__ zB, int do0, int do1) {
  __shared__ f16 st[64][136];
  int prob = blockIdx.y >> 4;
  if (prob ? !do1 : !do0) return;
  gemm_tile(prob, blockIdx.x, blockIdx.y, threadIdx.x, xt, h01, W0t, U0t,
            WU1t, cin0, zA, zB, st);
}

__global__ __launch_bounds__(256) void ln_gates2(
    const f16* __restrict__ zA, const f16* __restrict__ zB,
    const float* __restrict__ g0, const float* __restrict__ be0,
    const float* __restrict__ bs0, const float* __restrict__ g1,
    const float* __restrict__ be1, const float* __restrict__ bs1,
    const int* __restrict__ mask, int t,
    f16* __restrict__ h01, float* __restrict__ c0, float* __restrict__ c1,
    int do0, int do1) {
  __shared__ float act[2048];
  int layer = blockIdx.x >> 10;
  if (layer ? !do1 : !do0) return;
  ln_unit(layer, blockIdx.x & 1023, t, zA, zB, g0, be0, bs0, g1, be1, bs1,
          mask, h01, c0, c1, act);
}

// ---------------------------------------------------------------------------
// Head: out[b,:] = softmax(h1[b,:] @ Wd + bd); h1 = h01 cols [512,1024)
// ---------------------------------------------------------------------------
__global__ __launch_bounds__(64) void head_kernel(
    const f16* __restrict__ h01, const float* __restrict__ Wd,
    const float* __restrict__ bd, float* __restrict__ out) {
  __shared__ float hs[512];
  __shared__ float lg[16];
  int b = blockIdx.x, tid = threadIdx.x;
#pragma unroll
  for (int i = 0; i < 8; ++i)
    hs[tid + 64 * i] = (float)h01[(long)b * 1024 + 512 + tid + 64 * i];
  __syncthreads();
  if (tid < 14) {
    float s = bd[tid];
    for (int k = 0; k < 512; ++k) s += hs[k] * Wd[k * 14 + tid];
    lg[tid] = s;
  }
  __syncthreads();
  if (tid < 14) {
    float mx = lg[0];
#pragma unroll
    for (int i = 1; i < 14; ++i) mx = fmaxf(mx, lg[i]);
    float e = __expf(lg[tid] - mx);
    float den = 0.0f;
#pragma unroll
    for (int i = 0; i < 14; ++i) den += __expf(lg[i] - mx);
    out[(long)b * 14 + tid] = e / den;
  }
}

// ---------------------------------------------------------------------------
extern "C" void kernel_launch(void* const* d_in, const int* in_sizes, int n_in,
                              void* d_out, int out_size, void* d_ws, size_t ws_size,
                              hipStream_t stream) {
  const float* x   = (const float*)d_in[0];
  const int* mask  = (const int*)d_in[1];
  const float* W0  = (const float*)d_in[2];
  const float* U0w = (const float*)d_in[3];
  const float* b0  = (const float*)d_in[4];
  const float* g0  = (const float*)d_in[5];
  const float* be0 = (const float*)d_in[6];
  const float* W1  = (const float*)d_in[7];
  const float* U1w = (const float*)d_in[8];
  const float* b1  = (const float*)d_in[9];
  const float* g1  = (const float*)d_in[10];
  const float* be1 = (const float*)d_in[11];
  const float* Wd  = (const float*)d_in[12];
  const float* bd  = (const float*)d_in[13];
  float* out = (float*)d_out;

  char* p = (char*)d_ws;
  const size_t MB = (size_t)1 << 20;
  f16*   h01  = (f16*)(p + 0);               // 2 MiB  [1024][1024]
  float* c0   = (float*)(p + 2 * MB);        // 2 MiB
  float* c1   = (float*)(p + 4 * MB);        // 2 MiB
  f16*   zA   = (f16*)(p + 6 * MB);          // 4 MiB  [1024][2048] f16
  f16*   zB   = (f16*)(p + 10 * MB);         // 4 MiB
  f16*   W0t  = (f16*)(p + 14 * MB);         // 1.25 MiB
  f16*   U0t  = (f16*)(p + 14 * MB + 1310720);            // 2 MiB
  f16*   WU1t = (f16*)(p + 14 * MB + 1310720 + 2097152);  // 4 MiB
  f16*   z0x  = (f16*)(p + 32 * MB);         // 400 MiB -> ends 432 MiB

  const bool hoist = ws_size >= (size_t)432 * MB;

  // zero h01, c0, c1 (ws is re-poisoned before every call)
  hipMemsetAsync(p, 0, 6 * MB, stream);

  // weight prep
  transpose_f16<<<dim3(64, 10), 256, 0, stream>>>(W0,  W0t, 300, 2048, 320, 0);
  transpose_f16<<<dim3(64, 16), 256, 0, stream>>>(U0w, U0t, 512, 2048, 512, 0);
  transpose_f16<<<dim3(64, 16), 256, 0, stream>>>(W1,  WU1t, 512, 2048, 1024, 0);
  transpose_f16<<<dim3(64, 16), 256, 0, stream>>>(U1w, WU1t, 512, 2048, 1024, 512);

  if (hoist) {
    gemm_x0<<<1600, 256, 0, stream>>>(x, W0t, z0x);
  }

  // cooperative persistent loop; fallback to multi-launch on failure
  int coop = 0, dev = 0;
  hipGetDevice(&dev);
  hipDeviceGetAttribute(&coop, hipDeviceAttributeCooperativeLaunch, dev);

  bool launched = false;
  if (coop) {
    const float* x_ = x;
    const int* mask_ = mask;
    const float* g0_ = g0; const float* be0_ = be0; const float* bs0_ = b0;
    const float* g1_ = g1; const float* be1_ = be1; const float* bs1_ = b1;
    f16* h01_ = h01; float* c0_ = c0; float* c1_ = c1;
    const f16* W0t_ = W0t; const f16* U0t_ = U0t; const f16* WU1t_ = WU1t;
    const f16* z0x_ = hoist ? z0x : nullptr;
    f16* zA_ = zA; f16* zB_ = zB;
    void* ka[] = {&x_, &mask_, &g0_, &be0_, &bs0_, &g1_, &be1_, &bs1_,
                  &h01_, &c0_, &c1_, &W0t_, &U0t_, &WU1t_, &z0x_, &zA_, &zB_};
    hipError_t err = hipLaunchCooperativeKernel(
        (const void*)lstm_loop, dim3(512), dim3(256), ka, 0, stream);
    launched = (err == hipSuccess);
  }

  if (!launched) {
    for (int t = 0; t <= 100; ++t) {
      int do0 = (t < 100) ? 1 : 0;
      int do1 = (t >= 1) ? 1 : 0;
      const f16* cin0 = hoist ? (z0x + (long)t * 2097152) : nullptr;
      gemm_step<<<dim3(16, 32), 256, 0, stream>>>(
          x + (long)t * 300, h01, W0t, U0t, WU1t, cin0, zA, zB, do0, do1);
      ln_gates2<<<2048, 256, 0, stream>>>(
          zA, zB, g0, be0, b0, g1, be1, b1, mask, t, h01, c0, c1, do0, do1);
    }
  }

  head_kernel<<<1024, 64, 0, stream>>>(h01, Wd, bd, out);
}

// Round 7
// 5156.162 us; speedup vs baseline: 5.8872x; 5.8872x over previous
//
#include <hip/hip_runtime.h>

// ---------------------------------------------------------------------------
// LayerNorm-LSTM (2 layers) + softmax head.  B=1024 T=100 D=300 U=512 C=14
// Round 10:
//   - r6 coop kernel: 30ms. grid.sync+fence on 8 non-coherent XCD L2s
//     re-fetches all weights every half-iter (FETCH 4GB/dispatch) + VGPR
//     capped 128 -> spills.  Persistent path abandoned.
//   - back to multi-launch (r4 structure, fp32 z) with a real GEMM fix:
//     128x128 block tile (wave 64x64), 4-deep prefetch, launch_bounds(256,1)
//     -> ~210 VGPR, no spill, grid = 256 blocks = 1/CU.
//     MFMA:load 16:8 (was 8:6), B-duplication halved.
//   - x@W0 stays hoisted via gemm_x0 (457us measured); per-step gemm_x0
//     variant is the no-hoist fallback.
// ---------------------------------------------------------------------------

typedef _Float16 f16;
typedef _Float16 f16x8 __attribute__((ext_vector_type(8)));
typedef _Float16 f16x4 __attribute__((ext_vector_type(4)));
typedef float f32x4 __attribute__((ext_vector_type(4)));

// ---------------------------------------------------------------------------
// W [K,N] fp32 row-major -> Bt [N,Kp] f16 row-major at column offset k_off.
// ---------------------------------------------------------------------------
__global__ __launch_bounds__(256) void transpose_f16(
    const float* __restrict__ W, f16* __restrict__ Bt, int K, int N, int Kp,
    int k_off) {
  __shared__ float s[32][33];
  int n0 = blockIdx.x * 32, k0 = blockIdx.y * 32;
  int tid = threadIdx.x, c = tid & 31, r8 = tid >> 5;
  for (int rr = r8; rr < 32; rr += 8) {
    int k = k0 + rr;
    s[rr][c] = (k < K) ? W[(long)k * N + (n0 + c)] : 0.0f;
  }
  __syncthreads();
  for (int rr = r8; rr < 32; rr += 8)
    Bt[(long)(n0 + rr) * Kp + k_off + (k0 + c)] = (f16)s[c][rr];
}

// --------------------------- 64-wide (gemm_x0) -----------------------------
#define MFMAS(AF, BF)                                                                   \
  acc[0][0] = __builtin_amdgcn_mfma_f32_16x16x32_f16(AF[0], BF[0], acc[0][0], 0, 0, 0); \
  acc[0][1] = __builtin_amdgcn_mfma_f32_16x16x32_f16(AF[0], BF[1], acc[0][1], 0, 0, 0); \
  acc[1][0] = __builtin_amdgcn_mfma_f32_16x16x32_f16(AF[1], BF[0], acc[1][0], 0, 0, 0); \
  acc[1][1] = __builtin_amdgcn_mfma_f32_16x16x32_f16(AF[1], BF[1], acc[1][1], 0, 0, 0); \
  acc[2][0] = __builtin_amdgcn_mfma_f32_16x16x32_f16(AF[2], BF[0], acc[2][0], 0, 0, 0); \
  acc[2][1] = __builtin_amdgcn_mfma_f32_16x16x32_f16(AF[2], BF[1], acc[2][1], 0, 0, 0); \
  acc[3][0] = __builtin_amdgcn_mfma_f32_16x16x32_f16(AF[3], BF[0], acc[3][0], 0, 0, 0); \
  acc[3][1] = __builtin_amdgcn_mfma_f32_16x16x32_f16(AF[3], BF[1], acc[3][1], 0, 0, 0);

// ---------------------------------------------------------------------------
// x@W0: z0x = (f16) x_rows @ W0.  One block per 64-row stripe; x staged to
// LDS f16 once; 16 N-chunks from LDS.  full=1: rows are r=b*100+t (lda=300),
// dst z0x[t][b][:].  full=0: rows are b (lda passed), dst row r directly.
// ---------------------------------------------------------------------------
__global__ __launch_bounds__(256) void gemm_x0(
    const float* __restrict__ x, long lda, const f16* __restrict__ W0t,
    f16* __restrict__ z0x, int full) {
  __shared__ f16 xs[64][340];
  __shared__ f16 st[64][136];
  int tid = threadIdx.x;
  long bm0 = (long)blockIdx.x * 64;

  for (int p = 0; p < 20; ++p) {
    unsigned idx = (unsigned)tid + p * 256u;  // [0, 5120)
    unsigned r = idx / 80u, s = idx - r * 80u;
    f16x4 h4 = {};
    if (s < 75u) {
      f32x4 v = *(const f32x4*)(x + (bm0 + r) * lda + s * 4u);
      h4[0] = (f16)v[0]; h4[1] = (f16)v[1];
      h4[2] = (f16)v[2]; h4[3] = (f16)v[3];
    }
    *(f16x4*)&xs[r][s * 4u] = h4;
  }
  __syncthreads();

  int lane = tid & 63, w = tid >> 6;
  int l15 = lane & 15, quad = lane >> 4;

  for (int nc = 0; nc < 16; ++nc) {
    long bn0 = (long)nc * 128 + w * 32;
    const f16* bw = W0t + (bn0 + l15) * 320L + quad * 8;
    f32x4 acc[4][2] = {};
#pragma unroll
    for (int k0 = 0; k0 < 320; k0 += 32) {
      f16x8 af[4], bf[2];
#pragma unroll
      for (int i = 0; i < 4; ++i)
        af[i] = *(const f16x8*)&xs[l15 + i * 16][quad * 8 + k0];
      bf[0] = *(const f16x8*)(bw + k0);
      bf[1] = *(const f16x8*)(bw + 16 * 320 + k0);
      MFMAS(af, bf)
    }
    __syncthreads();
#pragma unroll
    for (int i = 0; i < 4; ++i)
#pragma unroll
      for (int j = 0; j < 2; ++j)
#pragma unroll
        for (int r = 0; r < 4; ++r)
          st[i * 16 + quad * 4 + r][w * 32 + j * 16 + l15] = (f16)acc[i][j][r];
    __syncthreads();
    {
      int r = tid >> 2, cc = (tid & 3) * 32;
      f16* dst;
      if (full) {
        unsigned rr = (unsigned)(bm0 + r);
        unsigned b = rr / 100u, t = rr - b * 100u;
        dst = z0x + (long)t * 2097152 + (long)b * 2048 + nc * 128 + cc;
      } else {
        dst = z0x + (bm0 + r) * 2048 + nc * 128 + cc;
      }
      const f16x8* s8 = (const f16x8*)&st[r][cc];
      f16x8* d8 = (f16x8*)dst;
      d8[0] = s8[0]; d8[1] = s8[1]; d8[2] = s8[2]; d8[3] = s8[3];
    }
  }
}

// --------------------------- 128x128 gemm_step -----------------------------
// wave tile 64x64: 4 A-frags x 4 B-frags, acc[4][4] f32x4 (64 VGPR).
#define LD8(AF, BF, A0, B0, LDB, K0)                       \
  AF[0] = *(const f16x8*)((A0) + (K0));                    \
  AF[1] = *(const f16x8*)((A0) + 16 * 1024 + (K0));        \
  AF[2] = *(const f16x8*)((A0) + 32 * 1024 + (K0));        \
  AF[3] = *(const f16x8*)((A0) + 48 * 1024 + (K0));        \
  BF[0] = *(const f16x8*)((B0) + (K0));                    \
  BF[1] = *(const f16x8*)((B0) + 16 * (LDB) + (K0));       \
  BF[2] = *(const f16x8*)((B0) + 32 * (LDB) + (K0));       \
  BF[3] = *(const f16x8*)((B0) + 48 * (LDB) + (K0));

#define MM16(AF, BF)                                                              \
  {                                                                               \
    _Pragma("unroll") for (int i_ = 0; i_ < 4; ++i_)                              \
    _Pragma("unroll") for (int j_ = 0; j_ < 4; ++j_)                              \
      acc[i_][j_] = __builtin_amdgcn_mfma_f32_16x16x32_f16(AF[i_], BF[j_],        \
                                                            acc[i_][j_], 0, 0, 0); \
  }

// 4-deep register-pipelined K-loop (KTOT in {512, 1024}).
#define GEMM_PIPE4W(A0, B0, LDB, KTOT)                           \
  {                                                              \
    f16x8 aA[4], bA[4], aB[4], bB[4];                            \
    f16x8 aC[4], bC[4], aD[4], bD[4];                            \
    LD8(aA, bA, A0, B0, LDB, 0)                                  \
    LD8(aB, bB, A0, B0, LDB, 32)                                 \
    LD8(aC, bC, A0, B0, LDB, 64)                                 \
    LD8(aD, bD, A0, B0, LDB, 96)                                 \
    for (int k0 = 0; k0 + 224 < (KTOT); k0 += 128) {             \
      MM16(aA, bA) LD8(aA, bA, A0, B0, LDB, k0 + 128)            \
      MM16(aB, bB) LD8(aB, bB, A0, B0, LDB, k0 + 160)            \
      MM16(aC, bC) LD8(aC, bC, A0, B0, LDB, k0 + 192)            \
      MM16(aD, bD) LD8(aD, bD, A0, B0, LDB, k0 + 224)            \
    }                                                            \
    MM16(aA, bA) MM16(aB, bB) MM16(aC, bC) MM16(aD, bD)          \
  }

// ---------------------------------------------------------------------------
// Combined per-step GEMM (pipelined layers), fp32 output:
//   y in [0,8):   zA[mstripe y]  = cin0 + h0 @ U0t          (z0 at step t)
//   y in [8,16):  zB[mstripe y-8] = h01 @ WU1t  (K=1024)    (z1 at step t-1)
// grid dim3(16,16) = 256 blocks = 1/CU.  launch_bounds(256,1): VGPR cap 512,
// ~210 used, no spill.
// ---------------------------------------------------------------------------
__global__ __launch_bounds__(256, 1) void gemm_step(
    const f16* __restrict__ h01, const f16* __restrict__ U0t,
    const f16* __restrict__ WU1t, const f16* __restrict__ cin0,
    float* __restrict__ zA, float* __restrict__ zB, int do0, int do1) {
  int y = blockIdx.y;
  int prob = y >> 3;
  if (prob ? !do1 : !do0) return;
  int tid = threadIdx.x;
  int lane = tid & 63, w = tid >> 6;
  int wr = w >> 1, wc = w & 1;
  int l15 = lane & 15, quad = lane >> 4;
  long bm0 = (long)(y & 7) * 128 + wr * 64;
  long bn0 = (long)blockIdx.x * 128 + wc * 64;
  long arow = (bm0 + l15) * 1024 + quad * 8;

  f32x4 acc[4][4] = {};

  if (prob == 0) {
    const f16* a0 = h01 + arow;  // h0 = cols [0,512)
    const f16* b0 = U0t + (bn0 + l15) * 512L + quad * 8;
    GEMM_PIPE4W(a0, b0, 512, 512)
  } else {
    const f16* a0 = h01 + arow;  // full h01 row, K=1024
    const f16* b0 = WU1t + (bn0 + l15) * 1024L + quad * 8;
    GEMM_PIPE4W(a0, b0, 1024, 1024)
  }

  float* Z = prob ? zB : zA;
#pragma unroll
  for (int i = 0; i < 4; ++i) {
    long row = bm0 + i * 16 + quad * 4;
#pragma unroll
    for (int j = 0; j < 4; ++j) {
      long col = bn0 + j * 16 + l15;
#pragma unroll
      for (int r = 0; r < 4; ++r) {
        float v = acc[i][j][r];
        if (prob == 0) v += (float)cin0[(row + r) * 2048 + col];
        Z[(row + r) * 2048 + col] = v;
      }
    }
  }
}

// ---------------------------------------------------------------------------
// Combined LN + gates + state update (fp32 z, vectorized):
//   blocks [0,1024)    : layer 0, z=zA, mask time t     (if do0)
//   blocks [1024,2048) : layer 1, z=zB, mask time t-1   (if do1)
// h stored into h01 (row stride 1024, layer offset 512*layer).
// ---------------------------------------------------------------------------
__global__ __launch_bounds__(256) void ln_gates2(
    const float* __restrict__ zA, const float* __restrict__ zB,
    const float* __restrict__ g0, const float* __restrict__ be0,
    const float* __restrict__ bs0, const float* __restrict__ g1,
    const float* __restrict__ be1, const float* __restrict__ bs1,
    const int* __restrict__ mask, int t,
    f16* __restrict__ h01, float* __restrict__ c0, float* __restrict__ c1,
    int do0, int do1) {
  __shared__ float act[2048];
  int layer = blockIdx.x >> 10;
  if (layer ? !do1 : !do0) return;
  int b = blockIdx.x & 1023;
  const float* z = layer ? zB : zA;
  const float* gamma = layer ? g1 : g0;
  const float* beta = layer ? be1 : be0;
  const float* bias = layer ? bs1 : bs0;
  f16* h = h01 + layer * 512;
  float* c = layer ? c1 : c0;
  int tm = layer ? (t - 1) : t;

  int tid = threadIdx.x;
  int w = tid >> 6, lane = tid & 63;

  const float* zb = z + (long)b * 2048 + w * 512;
  f32x4 zv[2];
  float sum = 0.0f, sq = 0.0f;
#pragma unroll
  for (int i = 0; i < 2; ++i) {
    f32x4 v = *(const f32x4*)(zb + lane * 4 + 256 * i);
    zv[i] = v;
#pragma unroll
    for (int e = 0; e < 4; ++e) {
      sum += v[e];
      sq += v[e] * v[e];
    }
  }
#pragma unroll
  for (int off = 32; off; off >>= 1) {
    sum += __shfl_xor(sum, off);
    sq += __shfl_xor(sq, off);
  }
  float mu = sum * (1.0f / 512.0f);
  float var = sq * (1.0f / 512.0f) - mu * mu;
  float is = rsqrtf(var + 1e-3f);

#pragma unroll
  for (int i = 0; i < 2; ++i) {
    int k = w * 512 + lane * 4 + 256 * i;
    f32x4 g = *(const f32x4*)(gamma + k);
    f32x4 be = *(const f32x4*)(beta + k);
    f32x4 bi = *(const f32x4*)(bias + k);
    f32x4 av;
#pragma unroll
    for (int e = 0; e < 4; ++e) {
      float val = g[e] * (zv[i][e] - mu) * is + be[e] + bi[e];
      float a;
      if (w == 2) {
        a = 2.0f / (1.0f + __expf(-2.0f * val)) - 1.0f;  // tanh
      } else {
        a = 1.0f / (1.0f + __expf(-val));                // sigmoid
      }
      av[e] = a;
    }
    *(f32x4*)(act + k) = av;
  }
  __syncthreads();

  bool m = mask[(long)b * 100 + tm] > 0;
#pragma unroll
  for (int i = 0; i < 2; ++i) {
    int u = tid + 256 * i;
    float co = c[(long)b * 512 + u];
    float ho = (float)h[(long)b * 1024 + u];
    float cn = act[512 + u] * co + act[u] * act[1024 + u];
    float th = 2.0f / (1.0f + __expf(-2.0f * cn)) - 1.0f;
    float hn = act[1536 + u] * th;
    h[(long)b * 1024 + u] = (f16)(m ? hn : ho);
    c[(long)b * 512 + u] = m ? cn : co;
  }
}

// ---------------------------------------------------------------------------
// Head: out[b,:] = softmax(h1[b,:] @ Wd + bd); h1 = h01 cols [512,1024)
// ---------------------------------------------------------------------------
__global__ __launch_bounds__(64) void head_kernel(
    const f16* __restrict__ h01, const float* __restrict__ Wd,
    const float* __restrict__ bd, float* __restrict__ out) {
  __shared__ float hs[512];
  __shared__ float lg[16];
  int b = blockIdx.x, tid = threadIdx.x;
#pragma unroll
  for (int i = 0; i < 8; ++i)
    hs[tid + 64 * i] = (float)h01[(long)b * 1024 + 512 + tid + 64 * i];
  __syncthreads();
  if (tid < 14) {
    float s = bd[tid];
    for (int k = 0; k < 512; ++k) s += hs[k] * Wd[k * 14 + tid];
    lg[tid] = s;
  }
  __syncthreads();
  if (tid < 14) {
    float mx = lg[0];
#pragma unroll
    for (int i = 1; i < 14; ++i) mx = fmaxf(mx, lg[i]);
    float e = __expf(lg[tid] - mx);
    float den = 0.0f;
#pragma unroll
    for (int i = 0; i < 14; ++i) den += __expf(lg[i] - mx);
    out[(long)b * 14 + tid] = e / den;
  }
}

// ---------------------------------------------------------------------------
extern "C" void kernel_launch(void* const* d_in, const int* in_sizes, int n_in,
                              void* d_out, int out_size, void* d_ws, size_t ws_size,
                              hipStream_t stream) {
  const float* x   = (const float*)d_in[0];
  const int* mask  = (const int*)d_in[1];
  const float* W0  = (const float*)d_in[2];
  const float* U0w = (const float*)d_in[3];
  const float* b0  = (const float*)d_in[4];
  const float* g0  = (const float*)d_in[5];
  const float* be0 = (const float*)d_in[6];
  const float* W1  = (const float*)d_in[7];
  const float* U1w = (const float*)d_in[8];
  const float* b1  = (const float*)d_in[9];
  const float* g1  = (const float*)d_in[10];
  const float* be1 = (const float*)d_in[11];
  const float* Wd  = (const float*)d_in[12];
  const float* bd  = (const float*)d_in[13];
  float* out = (float*)d_out;

  char* p = (char*)d_ws;
  const size_t MB = (size_t)1 << 20;
  f16*   h01  = (f16*)(p + 0);               // 2 MiB  [1024][1024]
  float* c0   = (float*)(p + 2 * MB);        // 2 MiB
  float* c1   = (float*)(p + 4 * MB);        // 2 MiB
  float* zA   = (float*)(p + 6 * MB);        // 8 MiB  [1024][2048] fp32
  float* zB   = (float*)(p + 14 * MB);       // 8 MiB
  f16*   W0t  = (f16*)(p + 22 * MB);         // 1.25 MiB
  f16*   U0t  = (f16*)(p + 22 * MB + 1310720);            // 2 MiB
  f16*   WU1t = (f16*)(p + 22 * MB + 1310720 + 2097152);  // 4 MiB -> ends ~29.25
  f16*   zX   = (f16*)(p + 30 * MB);         // 4 MiB  (per-step x@W0, fallback)
  f16*   z0x  = (f16*)(p + 34 * MB);         // 400 MiB -> ends 434 MiB

  const bool hoist = ws_size >= (size_t)434 * MB;

  // zero h01, c0, c1 (ws is re-poisoned before every call)
  hipMemsetAsync(p, 0, 6 * MB, stream);

  // weight prep
  transpose_f16<<<dim3(64, 10), 256, 0, stream>>>(W0,  W0t, 300, 2048, 320, 0);
  transpose_f16<<<dim3(64, 16), 256, 0, stream>>>(U0w, U0t, 512, 2048, 512, 0);
  transpose_f16<<<dim3(64, 16), 256, 0, stream>>>(W1,  WU1t, 512, 2048, 1024, 0);
  transpose_f16<<<dim3(64, 16), 256, 0, stream>>>(U1w, WU1t, 512, 2048, 1024, 512);

  if (hoist) {
    gemm_x0<<<1600, 256, 0, stream>>>(x, 300, W0t, z0x, 1);
  }

  // pipelined: iteration t computes z0(t) and z1(t-1) together.
  for (int t = 0; t <= 100; ++t) {
    int do0 = (t < 100) ? 1 : 0;
    int do1 = (t >= 1) ? 1 : 0;
    const f16* cin0;
    if (hoist) {
      cin0 = z0x + (long)t * 2097152;
    } else {
      if (do0) gemm_x0<<<16, 256, 0, stream>>>(x + (long)t * 300, 30000, W0t, zX, 0);
      cin0 = zX;
    }
    gemm_step<<<dim3(16, 16), 256, 0, stream>>>(
        h01, U0t, WU1t, cin0, zA, zB, do0, do1);
    ln_gates2<<<2048, 256, 0, stream>>>(
        zA, zB, g0, be0, b0, g1, be1, b1, mask, t, h01, c0, c1, do0, do1);
  }

  head_kernel<<<1024, 64, 0, stream>>>(h01, Wd, bd, out);
}